// Round 4
// baseline (990.817 us; speedup 1.0000x reference)
//
#include <hip/hip_runtime.h>

#define NNODES 100000
#define NEDGES 800000
#define NGRAPH 2500
#define DEG 8
#define NDIM 44
#define EDIM 13
#define HDIM 64
#define NHH 256   // HEADS*H

typedef __attribute__((ext_vector_type(8))) short bf16x8;
typedef __attribute__((ext_vector_type(4))) float f32x4;

__device__ __forceinline__ float rl(float v, int k) {
  return __int_as_float(__builtin_amdgcn_readlane(__float_as_int(v), k));
}
__device__ __forceinline__ float sigm(float x) { return 1.f / (1.f + __expf(-x)); }
__device__ __forceinline__ ushort f2b(float f) {       // fp32 -> bf16 RNE
  unsigned u = __float_as_uint(f);
  u += 0x7FFFu + ((u >> 16) & 1u);
  return (ushort)(u >> 16);
}
__device__ __forceinline__ float b2f(ushort b) {
  return __uint_as_float(((unsigned)b) << 16);
}
// position -> natural column permutation (wv stored position-major)
// pos = 64w + 32np + 2lr + b  ->  col = 64w + 32np + 16b + lr
__device__ __forceinline__ int poscol(int pos) {
  return (pos & 224) | ((pos & 1) << 4) | ((pos >> 1) & 15);
}

// ---------------- hh = h @ W_proj (fp32) + bf16 copy ----------------
__global__ __launch_bounds__(256) void k_proj(const float* __restrict__ h,
                                              const float* __restrict__ Wp,
                                              float* __restrict__ hh,
                                              ushort* __restrict__ hhb) {
  int g = blockIdx.x * 256 + threadIdx.x;      // grid exact: N*64 threads
  int n = g >> 6, c = g & 63;
  const float* hr = h + n * NDIM;
  float acc = 0.f;
  #pragma unroll
  for (int k = 0; k < NDIM; ++k) acc += hr[k] * Wp[k * HDIM + c];
  hh[g] = acc;
  hhb[g] = f2b(acc);
}

// ---------------- W_comb[i][k][pos] = (W_proj_e @ We[i])[k][poscol(pos)] ----------------
__global__ __launch_bounds__(256) void k_comb(const float* __restrict__ Wpe,
                                              const float* __restrict__ We,
                                              float* __restrict__ Wc) {
  int g = blockIdx.x * 256 + threadIdx.x;   // grid exact: 3*13*256 = 9984
  int i = g / (EDIM * NHH);
  int r = g % (EDIM * NHH);
  int k = r >> 8, pos = r & 255;
  int c = poscol(pos);
  const float* wpe = Wpe + k * HDIM;
  const float* we  = We + (size_t)i * HDIM * NHH + c;
  float acc = 0.f;
  #pragma unroll 8
  for (int d = 0; d < HDIM; ++d) acc += wpe[d] * we[(size_t)d * NHH];
  Wc[g] = acc;
}

// ---------------- WnT[i][c][k] = bf16(Wn[i][k][c])  (B-operand, k-contiguous) ----------------
__global__ __launch_bounds__(256) void k_tn(const float* __restrict__ Wn,
                                            ushort* __restrict__ WnT) {
  int g = blockIdx.x * 256 + threadIdx.x;   // grid exact: 3*256*64
  int i = g / (NHH * HDIM);
  int r = g % (NHH * HDIM);
  int c = r >> 6, k = r & 63;
  WnT[g] = f2b(Wn[(size_t)i * HDIM * NHH + k * NHH + c]);
}

// ---------------- WsT[i][c][kpos] = bf16(Ws[i][poscol(kpos)][c]) ----------------
__global__ __launch_bounds__(256) void k_ts(const float* __restrict__ Ws,
                                            ushort* __restrict__ WsT) {
  int g = blockIdx.x * 256 + threadIdx.x;   // grid exact: 3*64*256
  int i = g / (HDIM * NHH);
  int r = g % (HDIM * NHH);
  int c = r >> 8, kpos = r & 255;
  int k = poscol(kpos);
  WsT[g] = f2b(Ws[(size_t)i * NHH * HDIM + k * HDIM + c]);
}

// ---------------- wv = hh @ Wn[i] via MFMA; du/dv fused; position-major packed store ----------------
__global__ __launch_bounds__(256) void k_wv(const ushort* __restrict__ hhb,  // [N][64] bf16
                                            const ushort* __restrict__ WnT,  // [256][64] bf16
                                            const float* __restrict__ atr,   // [4][192]
                                            ushort* __restrict__ wvb,        // [N][256] bf16 pos-major
                                            float* __restrict__ du,
                                            float* __restrict__ dv) {
  int t = threadIdx.x, lane = t & 63, w = t >> 6;
  int lr = lane & 15, lg = lane >> 4;
  int base = blockIdx.x * 32;              // grid exact: N/32 = 3125
  // B fragments: natural col = 64w+16n+lr, k = ks*32 + lg*8 + 0..7
  bf16x8 bfr[4][2];
  #pragma unroll
  for (int n = 0; n < 4; ++n)
    #pragma unroll
    for (int ks = 0; ks < 2; ++ks)
      bfr[n][ks] = *(const bf16x8*)&WnT[(size_t)(64 * w + 16 * n + lr) * 64 + ks * 32 + lg * 8];
  float auv[4], avv[4];
  #pragma unroll
  for (int n = 0; n < 4; ++n) {
    auv[n] = atr[w * 192 + 16 * n + lr];
    avv[n] = atr[w * 192 + 128 + 16 * n + lr];
  }
  // A fragments: row = base+16m+lr, k = ks*32 + lg*8 + 0..7
  bf16x8 afr[2][2];
  #pragma unroll
  for (int m = 0; m < 2; ++m)
    #pragma unroll
    for (int ks = 0; ks < 2; ++ks)
      afr[m][ks] = *(const bf16x8*)&hhb[(size_t)(base + 16 * m + lr) * 64 + ks * 32 + lg * 8];
  f32x4 acc[2][4];
  #pragma unroll
  for (int m = 0; m < 2; ++m)
    #pragma unroll
    for (int n = 0; n < 4; ++n) acc[m][n] = (f32x4)(0.f);
  #pragma unroll
  for (int ks = 0; ks < 2; ++ks)
    #pragma unroll
    for (int m = 0; m < 2; ++m)
      #pragma unroll
      for (int n = 0; n < 4; ++n)
        acc[m][n] = __builtin_amdgcn_mfma_f32_16x16x32_bf16(afr[m][ks], bfr[n][ks], acc[m][n], 0, 0, 0);
  // packed store: dword(lo=col 64w+32np+lr [n=2np], hi=col +16 [n=2np+1]) at dword idx row*128+32w+16np+lr
  unsigned* wvp = (unsigned*)wvb;
  #pragma unroll
  for (int m = 0; m < 2; ++m)
    #pragma unroll
    for (int np = 0; np < 2; ++np)
      #pragma unroll
      for (int reg = 0; reg < 4; ++reg) {
        unsigned d;
        asm("v_cvt_pk_bf16_f32 %0, %1, %2" : "=v"(d)
            : "v"(acc[m][2 * np][reg]), "v"(acc[m][2 * np + 1][reg]));
        int row = base + 16 * m + lg * 4 + reg;
        wvp[(size_t)row * 128 + 32 * w + 16 * np + lr] = d;
      }
  // du/dv: head w dot over this wave's 64 cols, reduce across lr (16 lanes)
  #pragma unroll
  for (int m = 0; m < 2; ++m)
    #pragma unroll
    for (int reg = 0; reg < 4; ++reg) {
      float pu = 0.f, pv = 0.f;
      #pragma unroll
      for (int n = 0; n < 4; ++n) {
        pu += acc[m][n][reg] * auv[n];
        pv += acc[m][n][reg] * avv[n];
      }
      #pragma unroll
      for (int msk = 1; msk < 16; msk <<= 1) {
        pu += __shfl_xor(pu, msk, 64);
        pv += __shfl_xor(pv, msk, 64);
      }
      if (lr == 0) {
        int node = base + 16 * m + lg * 4 + reg;
        du[node * 4 + w] = pu;
        dv[node * 4 + w] = pv;
      }
    }
}

// ---------------- fused edge kernel: et = e_f @ W_comb + attn + softmax + agg ----------------
// block 256 = 4 waves; 1 node per wave per pass. Wave-uniform e_f/src -> scalar loads.
__global__ __launch_bounds__(256) void k_edge(const ushort* __restrict__ wvb,  // [N][256] bf16 pos-major
                                              const float* __restrict__ ef,
                                              const int* __restrict__ src,
                                              const float* __restrict__ Wc,   // [13][256] pos-major
                                              const float* __restrict__ atr,  // [4][192]
                                              const float* __restrict__ du,
                                              const float* __restrict__ dv,
                                              ushort* __restrict__ aggb) {    // [N][256] bf16 pos-major
  int t = threadIdx.x;
  int lane = t & 63;
  int w = __builtin_amdgcn_readfirstlane(t >> 6);   // wave-uniform for the compiler
  int hq = lane >> 4;
  int gw = blockIdx.x * 4 + w, nw = gridDim.x * 4;
  // Wc fragment: lane owns positions 4l..4l+3 for all 13 k-rows (52 VGPR)
  float4 wc[EDIM];
  #pragma unroll
  for (int k = 0; k < EDIM; ++k) wc[k] = *(const float4*)&Wc[k * NHH + 4 * lane];
  // ae fragment for this lane's positions (decode pos -> natural col)
  float ae4[4];
  #pragma unroll
  for (int i = 0; i < 4; ++i) {
    int pos = 4 * lane + i;
    ae4[i] = atr[hq * 192 + 64 + (poscol(pos) & 63)];
  }
  for (int n = gw; n < NNODES; n += nw) {
    // ---- wave-uniform src ids (scalar loads) ----
    const int* sp = src + n * DEG;
    int s8[8];
    #pragma unroll
    for (int j = 0; j < 8; ++j) s8[j] = sp[j];
    float dvn = dv[n * 4 + hq];
    // ---- u gather (bf16, 8B/lane) + du gather ----
    float4 u4[8]; float duj[8];
    #pragma unroll
    for (int j = 0; j < 8; ++j) {
      int s = s8[j];
      ushort4 ub = *(const ushort4*)&wvb[(size_t)s * NHH + 4 * lane];
      u4[j].x = b2f(ub.x); u4[j].y = b2f(ub.y); u4[j].z = b2f(ub.z); u4[j].w = b2f(ub.w);
      duj[j] = du[s * 4 + hq];
    }
    // ---- et[j] = e_f[e0+j] @ W_comb; e_f via wave-uniform loads, two halves ----
    float4 et4[8];
    const float4* efp = (const float4*)(ef + (size_t)n * (DEG * EDIM));
    {
      float eA[52];
      #pragma unroll
      for (int q = 0; q < 13; ++q) *(float4*)&eA[4 * q] = efp[q];
      #pragma unroll
      for (int j = 0; j < 4; ++j) {
        float4 a = make_float4(0.f, 0.f, 0.f, 0.f);
        #pragma unroll
        for (int k = 0; k < EDIM; ++k) {
          float e = eA[j * EDIM + k];
          a.x += e * wc[k].x; a.y += e * wc[k].y;
          a.z += e * wc[k].z; a.w += e * wc[k].w;
        }
        et4[j] = a;
      }
    }
    {
      float eB[52];
      #pragma unroll
      for (int q = 0; q < 13; ++q) *(float4*)&eB[4 * q] = efp[13 + q];
      #pragma unroll
      for (int j = 0; j < 4; ++j) {
        float4 a = make_float4(0.f, 0.f, 0.f, 0.f);
        #pragma unroll
        for (int k = 0; k < EDIM; ++k) {
          float e = eB[j * EDIM + k];
          a.x += e * wc[k].x; a.y += e * wc[k].y;
          a.z += e * wc[k].z; a.w += e * wc[k].w;
        }
        et4[4 + j] = a;
      }
    }
    // ---- attention logits: du[src] + et.ae + dv[n], leaky relu ----
    float att[8];
    #pragma unroll
    for (int j = 0; j < 8; ++j) {
      float s = et4[j].x * ae4[0] + et4[j].y * ae4[1] + et4[j].z * ae4[2] + et4[j].w * ae4[3];
      #pragma unroll
      for (int m = 1; m < 16; m <<= 1) s += __shfl_xor(s, m, 64);
      float a = duj[j] + s + dvn;
      att[j] = (a >= 0.f) ? a : 0.2f * a;
    }
    // ---- softmax over the 8 incoming edges (per head, in-lane) ----
    float mx = att[0];
    #pragma unroll
    for (int j = 1; j < 8; ++j) mx = fmaxf(mx, att[j]);
    float ex[8], den = 0.f;
    #pragma unroll
    for (int j = 0; j < 8; ++j) { ex[j] = __expf(att[j] - mx); den += ex[j]; }
    float inv = 1.f / den;
    // ---- agg = sum_j score * u * et ----
    float4 a4 = make_float4(0.f, 0.f, 0.f, 0.f);
    #pragma unroll
    for (int j = 0; j < 8; ++j) {
      float sc = ex[j] * inv;
      a4.x += sc * u4[j].x * et4[j].x;
      a4.y += sc * u4[j].y * et4[j].y;
      a4.z += sc * u4[j].z * et4[j].z;
      a4.w += sc * u4[j].w * et4[j].w;
    }
    ushort4 ob;
    ob.x = f2b(a4.x); ob.y = f2b(a4.y); ob.z = f2b(a4.z); ob.w = f2b(a4.w);
    *(ushort4*)&aggb[(size_t)n * NHH + 4 * lane] = ob;
  }
}

// ---------------- hh += agg @ W_scale[i] + conv_b[i] via MFMA; hhb refresh ----------------
__global__ __launch_bounds__(256) void k_scale(const ushort* __restrict__ aggb,  // [N][256] bf16 pos-major
                                               const ushort* __restrict__ WsT,   // [64][256] bf16 k-permuted
                                               const float* __restrict__ cb,     // [64]
                                               float* __restrict__ hh,
                                               ushort* __restrict__ hhb) {
  int t = threadIdx.x, lane = t & 63, w = t >> 6;
  int lr = lane & 15, lg = lane >> 4;
  int base = blockIdx.x * 32;              // grid exact: N/32 = 3125
  int mrow = w & 1, npair = w >> 1;
  // B fragments: col = 32*npair + 16n + lr, kpos = ks*32 + lg*8
  bf16x8 bfr[2][8];
  #pragma unroll
  for (int n = 0; n < 2; ++n)
    #pragma unroll
    for (int ks = 0; ks < 8; ++ks)
      bfr[n][ks] = *(const bf16x8*)&WsT[(size_t)(32 * npair + 16 * n + lr) * NHH + ks * 32 + lg * 8];
  // A fragments: row = base + 16*mrow + lr
  bf16x8 afr[8];
  #pragma unroll
  for (int ks = 0; ks < 8; ++ks)
    afr[ks] = *(const bf16x8*)&aggb[(size_t)(base + 16 * mrow + lr) * NHH + ks * 32 + lg * 8];
  f32x4 acc[2];
  acc[0] = (f32x4)(0.f); acc[1] = (f32x4)(0.f);
  #pragma unroll
  for (int ks = 0; ks < 8; ++ks)
    #pragma unroll
    for (int n = 0; n < 2; ++n)
      acc[n] = __builtin_amdgcn_mfma_f32_16x16x32_bf16(afr[ks], bfr[n][ks], acc[n], 0, 0, 0);
  #pragma unroll
  for (int n = 0; n < 2; ++n)
    #pragma unroll
    for (int reg = 0; reg < 4; ++reg) {
      int row = base + 16 * mrow + lg * 4 + reg;
      int col = 32 * npair + 16 * n + lr;
      float v = hh[row * HDIM + col] + acc[n][reg] + cb[col];
      hh[row * HDIM + col] = v;
      hhb[row * HDIM + col] = f2b(v);
    }
}

// ---------------- Set2Set LSTM step (1 wave per graph) ----------------
__global__ __launch_bounds__(64) void k_lstm(const float* __restrict__ qstar,  // [B][128]
                                             const float* __restrict__ Wih,    // [256][128]
                                             const float* __restrict__ Whh,    // [256][64]
                                             const float* __restrict__ bih,
                                             const float* __restrict__ bhh,
                                             float* __restrict__ hx,
                                             float* __restrict__ cx) {
  int b = blockIdx.x, u = threadIdx.x;
  const float* qs = qstar + b * 128;
  float hxv = hx[b * 64 + u];
  float g4[4];
  #pragma unroll
  for (int gi = 0; gi < 4; ++gi) {
    int g = gi * 64 + u;
    const float* wi = Wih + g * 128;
    const float* wh = Whh + g * 64;
    float acc = bih[g] + bhh[g];
    for (int k = 0; k < 128; ++k) acc += qs[k] * wi[k];
    for (int k = 0; k < 64; ++k) acc += rl(hxv, k) * wh[k];
    g4[gi] = acc;
  }
  float ig = sigm(g4[0]), fg = sigm(g4[1]), gg = tanhf(g4[2]), og = sigm(g4[3]);
  float c = fg * cx[b * 64 + u] + ig * gg;
  cx[b * 64 + u] = c;
  hx[b * 64 + u] = og * tanhf(c);
}

// ---------------- Set2Set attention + readout (1 wave per graph, 40 nodes) ----------------
__global__ __launch_bounds__(64) void k_readout(const float* __restrict__ hh,
                                                const float* __restrict__ hx,
                                                float* __restrict__ qstar) {
  int b = blockIdx.x, lane = threadIdx.x;
  float qv = hx[b * 64 + lane];
  const float* hb = hh + (size_t)b * 40 * HDIM;
  float scm = -1e30f;
  if (lane < 40) {
    float acc = 0.f;
    for (int k = 0; k < 64; ++k) acc += hb[lane * 64 + k] * rl(qv, k);
    scm = acc;
  }
  float mx = scm;
  #pragma unroll
  for (int m = 1; m < 64; m <<= 1) mx = fmaxf(mx, __shfl_xor(mx, m, 64));
  float ex = (lane < 40) ? __expf(scm - mx) : 0.f;
  float den = ex;
  #pragma unroll
  for (int m = 1; m < 64; m <<= 1) den += __shfl_xor(den, m, 64);
  float alpha = ex / den;
  float ro = 0.f;
  for (int m = 0; m < 40; ++m) ro += rl(alpha, m) * hb[m * 64 + lane];
  qstar[b * 128 + lane] = qv;
  qstar[b * 128 + 64 + lane] = ro;
}

// ---------------- out = q_star @ W_out + b_out ----------------
__global__ __launch_bounds__(256) void k_out(const float* __restrict__ qstar,
                                             const float* __restrict__ Wout,  // [128][64]
                                             const float* __restrict__ bout,
                                             float* __restrict__ out) {
  int g = blockIdx.x * 256 + threadIdx.x;   // grid exact: B*64
  int b = g >> 6, c = g & 63;
  const float* qs = qstar + b * 128;
  float acc = bout[c];
  #pragma unroll 4
  for (int k = 0; k < 128; ++k) acc += qs[k] * Wout[k * 64 + c];
  out[g] = acc;
}

extern "C" void kernel_launch(void* const* d_in, const int* in_sizes, int n_in,
                              void* d_out, int out_size, void* d_ws, size_t ws_size,
                              hipStream_t stream) {
  const float* h    = (const float*)d_in[0];
  const float* e_f  = (const float*)d_in[1];
  const int*   src  = (const int*)  d_in[2];
  // d_in[3] = dst (structure: e/8), d_in[4] = graph_id (structure: n/40) — implicit
  const float* Wp   = (const float*)d_in[5];
  const float* Wpe  = (const float*)d_in[6];
  const float* Wn   = (const float*)d_in[7];
  const float* We   = (const float*)d_in[8];
  const float* atr  = (const float*)d_in[9];
  const float* Wsc  = (const float*)d_in[10];
  const float* cb   = (const float*)d_in[11];
  const float* Wih  = (const float*)d_in[12];
  const float* Whh  = (const float*)d_in[13];
  const float* bih  = (const float*)d_in[14];
  const float* bhh  = (const float*)d_in[15];
  const float* Wout = (const float*)d_in[16];
  const float* bout = (const float*)d_in[17];
  float* out = (float*)d_out;

  float* ws = (float*)d_ws;
  float* hh    = ws;                            // N*64 fp32
  float* du    = hh  + (size_t)NNODES * HDIM;   // N*4
  float* dv    = du  + (size_t)NNODES * 4;      // N*4
  float* qstar = dv  + (size_t)NNODES * 4;      // B*128
  float* hx    = qstar + (size_t)NGRAPH * 128;  // B*64
  float* cx    = hx    + (size_t)NGRAPH * 64;   // B*64
  float* Wc    = cx    + (size_t)NGRAPH * 64;   // 3*13*256
  ushort* hhb  = (ushort*)(Wc + 3 * EDIM * NHH);          // N*64 bf16
  ushort* wvb  = hhb + (size_t)NNODES * HDIM;             // N*256 bf16 (pos-major)
  ushort* aggb = wvb + (size_t)NNODES * NHH;              // N*256 bf16 (pos-major)
  ushort* WnT  = aggb + (size_t)NNODES * NHH;             // 3*256*64 bf16
  ushort* WsT  = WnT + (size_t)3 * NHH * HDIM;            // 3*64*256 bf16 (k-permuted)

  // zero set2set state (q_star, hx, cx contiguous)
  hipMemsetAsync(qstar, 0, (size_t)NGRAPH * (128 + 64 + 64) * sizeof(float), stream);

  k_comb<<<3 * EDIM * NHH / 256, 256, 0, stream>>>(Wpe, We, Wc);
  k_tn<<<3 * NHH * HDIM / 256, 256, 0, stream>>>(Wn, WnT);
  k_ts<<<3 * HDIM * NHH / 256, 256, 0, stream>>>(Wsc, WsT);
  k_proj<<<NNODES * HDIM / 256, 256, 0, stream>>>(h, Wp, hh, hhb);

  for (int i = 0; i < 3; ++i) {
    const float* atr_i = atr + (size_t)i * 4 * 192;
    const float* Wc_i  = Wc  + (size_t)i * EDIM * NHH;
    const ushort* WnT_i = WnT + (size_t)i * NHH * HDIM;
    const ushort* WsT_i = WsT + (size_t)i * HDIM * NHH;
    const float* cb_i  = cb  + (size_t)i * 64;
    k_wv<<<NNODES / 32, 256, 0, stream>>>(hhb, WnT_i, atr_i, wvb, du, dv);
    k_edge<<<4096, 256, 0, stream>>>(wvb, e_f, src, Wc_i, atr_i, du, dv, aggb);
    k_scale<<<NNODES / 32, 256, 0, stream>>>(aggb, WsT_i, cb_i, hh, hhb);
  }

  for (int t = 0; t < 2; ++t) {
    k_lstm<<<NGRAPH, 64, 0, stream>>>(qstar, Wih, Whh, bih, bhh, hx, cx);
    k_readout<<<NGRAPH, 64, 0, stream>>>(hh, hx, qstar);
  }

  k_out<<<NGRAPH * 64 / 256, 256, 0, stream>>>(qstar, Wout, bout, out);
}

// Round 5
// 821.760 us; speedup vs baseline: 1.2057x; 1.2057x over previous
//
#include <hip/hip_runtime.h>

#define NNODES 100000
#define NEDGES 800000
#define NGRAPH 2500
#define DEG 8
#define NDIM 44
#define EDIM 13
#define HDIM 64
#define NHH 256   // HEADS*H

typedef __attribute__((ext_vector_type(8))) short bf16x8;
typedef __attribute__((ext_vector_type(4))) float f32x4;

__device__ __forceinline__ float rl(float v, int k) {
  return __int_as_float(__builtin_amdgcn_readlane(__float_as_int(v), k));
}
__device__ __forceinline__ float sigm(float x) { return 1.f / (1.f + __expf(-x)); }
__device__ __forceinline__ ushort f2b(float f) {       // fp32 -> bf16 RNE
  unsigned u = __float_as_uint(f);
  u += 0x7FFFu + ((u >> 16) & 1u);
  return (ushort)(u >> 16);
}
__device__ __forceinline__ float b2f(ushort b) {
  return __uint_as_float(((unsigned)b) << 16);
}
// position -> natural column permutation (wv stored position-major)
// pos = 64w + 32np + 2lr + b  ->  col = 64w + 32np + 16b + lr
__device__ __forceinline__ int poscol(int pos) {
  return (pos & 224) | ((pos & 1) << 4) | ((pos >> 1) & 15);
}

// ---------------- hh = h @ W_proj (fp32) + bf16 copy ----------------
__global__ __launch_bounds__(256) void k_proj(const float* __restrict__ h,
                                              const float* __restrict__ Wp,
                                              float* __restrict__ hh,
                                              ushort* __restrict__ hhb) {
  int g = blockIdx.x * 256 + threadIdx.x;      // grid exact: N*64 threads
  int n = g >> 6, c = g & 63;
  const float* hr = h + n * NDIM;
  float acc = 0.f;
  #pragma unroll
  for (int k = 0; k < NDIM; ++k) acc += hr[k] * Wp[k * HDIM + c];
  hh[g] = acc;
  hhb[g] = f2b(acc);
}

// ---------------- W_comb[i][k][pos] = (W_proj_e @ We[i])[k][poscol(pos)] ----------------
__global__ __launch_bounds__(256) void k_comb(const float* __restrict__ Wpe,
                                              const float* __restrict__ We,
                                              float* __restrict__ Wc) {
  int g = blockIdx.x * 256 + threadIdx.x;   // grid exact: 3*13*256 = 9984
  int i = g / (EDIM * NHH);
  int r = g % (EDIM * NHH);
  int k = r >> 8, pos = r & 255;
  int c = poscol(pos);
  const float* wpe = Wpe + k * HDIM;
  const float* we  = We + (size_t)i * HDIM * NHH + c;
  float acc = 0.f;
  #pragma unroll 8
  for (int d = 0; d < HDIM; ++d) acc += wpe[d] * we[(size_t)d * NHH];
  Wc[g] = acc;
}

// ---------------- Wcb[i][pos][k] = bf16(Wc[i][k][pos]), k padded to 32 ----------------
__global__ __launch_bounds__(256) void k_wcb(const float* __restrict__ Wc,
                                             ushort* __restrict__ Wcb) {
  int g = blockIdx.x * 256 + threadIdx.x;   // grid exact: 3*256*32 = 24576
  int i = g / (NHH * 32);
  int r = g % (NHH * 32);
  int pos = r >> 5, k = r & 31;
  Wcb[g] = (k < EDIM) ? f2b(Wc[(size_t)(i * EDIM + k) * NHH + pos]) : (ushort)0;
}

// ---------------- wqb[i][h][k] = bf16( sum_c Wc[i][k][head h cols] * ae[h][c] ) ----------------
__global__ __launch_bounds__(256) void k_wqb(const float* __restrict__ Wc,
                                             const float* __restrict__ atr,  // [3][4][192]
                                             ushort* __restrict__ wqb) {
  int g = blockIdx.x * 256 + threadIdx.x;   // grid exact: 3*16*32 = 1536
  int i = g / (16 * 32);
  int r = g % (16 * 32);
  int hcol = r >> 5, k = r & 31;
  float acc = 0.f;
  if (hcol < 4 && k < EDIM) {
    const float* wck = Wc + (size_t)(i * EDIM + k) * NHH + 64 * hcol;
    const float* ae = atr + (size_t)i * 768 + hcol * 192 + 64;
    #pragma unroll 8
    for (int p = 0; p < 64; ++p) {
      int c = (p & 32) | ((p & 1) << 4) | ((p >> 1) & 15);  // poscol within head
      acc += wck[p] * ae[c];
    }
  }
  wqb[g] = (hcol < 4 && k < EDIM) ? f2b(acc) : (ushort)0;
}

// ---------------- efb[e][16] = bf16(e_f[e][0..12]), pad k 13..15 and rows >= E ----------------
__global__ __launch_bounds__(256) void k_ef(const float* __restrict__ ef,
                                            ushort* __restrict__ efb) {
  int g = blockIdx.x * 256 + threadIdx.x;   // grid exact: (E+16)*16/256
  int e = g >> 4, k = g & 15;
  efb[g] = (e < NEDGES && k < EDIM) ? f2b(ef[(size_t)e * EDIM + k]) : (ushort)0;
}

// ---------------- WnT[i][c][k] = bf16(Wn[i][k][c])  (B-operand, k-contiguous) ----------------
__global__ __launch_bounds__(256) void k_tn(const float* __restrict__ Wn,
                                            ushort* __restrict__ WnT) {
  int g = blockIdx.x * 256 + threadIdx.x;   // grid exact: 3*256*64
  int i = g / (NHH * HDIM);
  int r = g % (NHH * HDIM);
  int c = r >> 6, k = r & 63;
  WnT[g] = f2b(Wn[(size_t)i * HDIM * NHH + k * NHH + c]);
}

// ---------------- WsT[i][c][kpos] = bf16(Ws[i][poscol(kpos)][c]) ----------------
__global__ __launch_bounds__(256) void k_ts(const float* __restrict__ Ws,
                                            ushort* __restrict__ WsT) {
  int g = blockIdx.x * 256 + threadIdx.x;   // grid exact: 3*64*256
  int i = g / (HDIM * NHH);
  int r = g % (HDIM * NHH);
  int c = r >> 8, kpos = r & 255;
  int k = poscol(kpos);
  WsT[g] = f2b(Ws[(size_t)i * NHH * HDIM + k * HDIM + c]);
}

// ---------------- wv = hh @ Wn[i] via MFMA; du/dv fused; position-major packed store ----------------
__global__ __launch_bounds__(256) void k_wv(const ushort* __restrict__ hhb,  // [N][64] bf16
                                            const ushort* __restrict__ WnT,  // [256][64] bf16
                                            const float* __restrict__ atr,   // [4][192]
                                            ushort* __restrict__ wvb,        // [N][256] bf16 pos-major
                                            float* __restrict__ du,
                                            float* __restrict__ dv) {
  int t = threadIdx.x, lane = t & 63, w = t >> 6;
  int lr = lane & 15, lg = lane >> 4;
  int base = blockIdx.x * 32;              // grid exact: N/32 = 3125
  bf16x8 bfr[4][2];
  #pragma unroll
  for (int n = 0; n < 4; ++n)
    #pragma unroll
    for (int ks = 0; ks < 2; ++ks)
      bfr[n][ks] = *(const bf16x8*)&WnT[(size_t)(64 * w + 16 * n + lr) * 64 + ks * 32 + lg * 8];
  float auv[4], avv[4];
  #pragma unroll
  for (int n = 0; n < 4; ++n) {
    auv[n] = atr[w * 192 + 16 * n + lr];
    avv[n] = atr[w * 192 + 128 + 16 * n + lr];
  }
  bf16x8 afr[2][2];
  #pragma unroll
  for (int m = 0; m < 2; ++m)
    #pragma unroll
    for (int ks = 0; ks < 2; ++ks)
      afr[m][ks] = *(const bf16x8*)&hhb[(size_t)(base + 16 * m + lr) * 64 + ks * 32 + lg * 8];
  f32x4 acc[2][4];
  #pragma unroll
  for (int m = 0; m < 2; ++m)
    #pragma unroll
    for (int n = 0; n < 4; ++n) acc[m][n] = (f32x4)(0.f);
  #pragma unroll
  for (int ks = 0; ks < 2; ++ks)
    #pragma unroll
    for (int m = 0; m < 2; ++m)
      #pragma unroll
      for (int n = 0; n < 4; ++n)
        acc[m][n] = __builtin_amdgcn_mfma_f32_16x16x32_bf16(afr[m][ks], bfr[n][ks], acc[m][n], 0, 0, 0);
  unsigned* wvp = (unsigned*)wvb;
  #pragma unroll
  for (int m = 0; m < 2; ++m)
    #pragma unroll
    for (int np = 0; np < 2; ++np)
      #pragma unroll
      for (int reg = 0; reg < 4; ++reg) {
        unsigned d;
        asm("v_cvt_pk_bf16_f32 %0, %1, %2" : "=v"(d)
            : "v"(acc[m][2 * np][reg]), "v"(acc[m][2 * np + 1][reg]));
        int row = base + 16 * m + lg * 4 + reg;
        wvp[(size_t)row * 128 + 32 * w + 16 * np + lr] = d;
      }
  #pragma unroll
  for (int m = 0; m < 2; ++m)
    #pragma unroll
    for (int reg = 0; reg < 4; ++reg) {
      float pu = 0.f, pv = 0.f;
      #pragma unroll
      for (int n = 0; n < 4; ++n) {
        pu += acc[m][n][reg] * auv[n];
        pv += acc[m][n][reg] * avv[n];
      }
      #pragma unroll
      for (int msk = 1; msk < 16; msk <<= 1) {
        pu += __shfl_xor(pu, msk, 64);
        pv += __shfl_xor(pv, msk, 64);
      }
      if (lr == 0) {
        int node = base + 16 * m + lg * 4 + reg;
        du[node * 4 + w] = pu;
        dv[node * 4 + w] = pv;
      }
    }
}

// ---------------- fused edge kernel: MFMA et + MFMA attn + softmax + agg ----------------
// block 256 = 4 waves; 1 node per wave per pass. Per-wave LDS slice, no barriers.
__global__ __launch_bounds__(256) void k_edge(const ushort* __restrict__ wvb,  // [N][256] bf16 pos-major
                                              const ushort* __restrict__ efb,  // [E+16][16] bf16
                                              const int* __restrict__ src,
                                              const ushort* __restrict__ Wcb,  // [256][32] bf16
                                              const ushort* __restrict__ wqb,  // [16][32] bf16
                                              const float* __restrict__ du,
                                              const float* __restrict__ dv,
                                              ushort* __restrict__ aggb) {     // [N][256] bf16 pos-major
  __shared__ float et_lds[4][8][256];   // 32 KB, per-wave slices
  int t = threadIdx.x;
  int lane = t & 63, w = t >> 6;
  int lr = lane & 15, lg = lane >> 4;
  int hq = lg;                           // head = (4*lane)>>6 = lane>>4
  int gw = blockIdx.x * 4 + w, nw = gridDim.x * 4;
  // resident B fragments: Wcb (16 col-groups) + wq
  bf16x8 wcf[16];
  #pragma unroll
  for (int q = 0; q < 16; ++q)
    wcf[q] = *(const bf16x8*)&Wcb[(size_t)(16 * q + lr) * 32 + lg * 8];
  bf16x8 wqf = *(const bf16x8*)&wqb[(size_t)lr * 32 + lg * 8];
  float* myet = &et_lds[w][0][0];
  for (int n = gw; n < NNODES; n += nw) {
    int e0 = n * DEG;
    // ---- A fragment: row = edge lr, k = lg*8..+7 (zero for k>=16) ----
    bf16x8 af = (bf16x8)(short)0;
    if (lg < 2) af = *(const bf16x8*)&efb[(size_t)(e0 + lr) * 16 + lg * 8];
    // ---- src ids + gathers ----
    int sv = src[e0 + (lane & 7)];
    float dvn = dv[n * 4 + hq];
    uint2 ub[8]; float duj[8];
    #pragma unroll
    for (int j = 0; j < 8; ++j) {
      int s = __builtin_amdgcn_readlane(sv, j);
      ub[j] = *(const uint2*)&wvb[(size_t)s * NHH + 4 * lane];
      duj[j] = du[s * 4 + hq];
    }
    // ---- attn-e MFMA: D[j][h] at lane lr=h, lg=j>>2, reg=j&3 ----
    f32x4 aq = __builtin_amdgcn_mfma_f32_16x16x32_bf16(af, wqf, (f32x4)(0.f), 0, 0, 0);
    // ---- et MFMAs: D[j][pos 16q+lr]; spill rows 0-7 to LDS ----
    #pragma unroll
    for (int n4 = 0; n4 < 4; ++n4) {
      f32x4 ac[4];
      #pragma unroll
      for (int q = 0; q < 4; ++q)
        ac[q] = __builtin_amdgcn_mfma_f32_16x16x32_bf16(af, wcf[n4 * 4 + q], (f32x4)(0.f), 0, 0, 0);
      if (lg < 2) {
        #pragma unroll
        for (int q = 0; q < 4; ++q)
          #pragma unroll
          for (int reg = 0; reg < 4; ++reg)
            myet[(lg * 4 + reg) * 256 + 16 * (n4 * 4 + q) + lr] = ac[q][reg];
      }
    }
    // ---- attention logits: du[src] + attn_e + dv[n], leaky relu ----
    float att[8];
    #pragma unroll
    for (int j = 0; j < 8; ++j) {
      float ae = __shfl(aq[j & 3], 16 * (j >> 2) + hq, 64);
      float a = duj[j] + ae + dvn;
      att[j] = (a >= 0.f) ? a : 0.2f * a;
    }
    // ---- softmax over 8 edges (in-lane) ----
    float mx = att[0];
    #pragma unroll
    for (int j = 1; j < 8; ++j) mx = fmaxf(mx, att[j]);
    float ex[8], den = 0.f;
    #pragma unroll
    for (int j = 0; j < 8; ++j) { ex[j] = __expf(att[j] - mx); den += ex[j]; }
    float inv = 1.f / den;
    // ---- agg = sum_j score * u * et (et rows from LDS) ----
    float4 a4 = make_float4(0.f, 0.f, 0.f, 0.f);
    #pragma unroll
    for (int j = 0; j < 8; ++j) {
      float4 etj = *(const float4*)&myet[j * 256 + 4 * lane];
      float sc = ex[j] * inv;
      float u0 = __uint_as_float(ub[j].x << 16);
      float u1 = __uint_as_float(ub[j].x & 0xFFFF0000u);
      float u2 = __uint_as_float(ub[j].y << 16);
      float u3 = __uint_as_float(ub[j].y & 0xFFFF0000u);
      a4.x += sc * u0 * etj.x;
      a4.y += sc * u1 * etj.y;
      a4.z += sc * u2 * etj.z;
      a4.w += sc * u3 * etj.w;
    }
    unsigned d0, d1;
    asm("v_cvt_pk_bf16_f32 %0, %1, %2" : "=v"(d0) : "v"(a4.x), "v"(a4.y));
    asm("v_cvt_pk_bf16_f32 %0, %1, %2" : "=v"(d1) : "v"(a4.z), "v"(a4.w));
    uint2 ob; ob.x = d0; ob.y = d1;
    *(uint2*)&aggb[(size_t)n * NHH + 4 * lane] = ob;
  }
}

// ---------------- hh += agg @ W_scale[i] + conv_b[i] via MFMA; hhb refresh ----------------
__global__ __launch_bounds__(256) void k_scale(const ushort* __restrict__ aggb,  // [N][256] bf16 pos-major
                                               const ushort* __restrict__ WsT,   // [64][256] bf16 k-permuted
                                               const float* __restrict__ cb,     // [64]
                                               float* __restrict__ hh,
                                               ushort* __restrict__ hhb) {
  int t = threadIdx.x, lane = t & 63, w = t >> 6;
  int lr = lane & 15, lg = lane >> 4;
  int base = blockIdx.x * 32;              // grid exact: N/32 = 3125
  int mrow = w & 1, npair = w >> 1;
  bf16x8 bfr[2][8];
  #pragma unroll
  for (int n = 0; n < 2; ++n)
    #pragma unroll
    for (int ks = 0; ks < 8; ++ks)
      bfr[n][ks] = *(const bf16x8*)&WsT[(size_t)(32 * npair + 16 * n + lr) * NHH + ks * 32 + lg * 8];
  bf16x8 afr[8];
  #pragma unroll
  for (int ks = 0; ks < 8; ++ks)
    afr[ks] = *(const bf16x8*)&aggb[(size_t)(base + 16 * mrow + lr) * NHH + ks * 32 + lg * 8];
  f32x4 acc[2];
  acc[0] = (f32x4)(0.f); acc[1] = (f32x4)(0.f);
  #pragma unroll
  for (int ks = 0; ks < 8; ++ks)
    #pragma unroll
    for (int n = 0; n < 2; ++n)
      acc[n] = __builtin_amdgcn_mfma_f32_16x16x32_bf16(afr[ks], bfr[n][ks], acc[n], 0, 0, 0);
  #pragma unroll
  for (int n = 0; n < 2; ++n)
    #pragma unroll
    for (int reg = 0; reg < 4; ++reg) {
      int row = base + 16 * mrow + lg * 4 + reg;
      int col = 32 * npair + 16 * n + lr;
      float v = hh[row * HDIM + col] + acc[n][reg] + cb[col];
      hh[row * HDIM + col] = v;
      hhb[row * HDIM + col] = f2b(v);
    }
}

// ---------------- Set2Set LSTM step (1 wave per graph) ----------------
__global__ __launch_bounds__(64) void k_lstm(const float* __restrict__ qstar,  // [B][128]
                                             const float* __restrict__ Wih,    // [256][128]
                                             const float* __restrict__ Whh,    // [256][64]
                                             const float* __restrict__ bih,
                                             const float* __restrict__ bhh,
                                             float* __restrict__ hx,
                                             float* __restrict__ cx) {
  int b = blockIdx.x, u = threadIdx.x;
  const float* qs = qstar + b * 128;
  float hxv = hx[b * 64 + u];
  float g4[4];
  #pragma unroll
  for (int gi = 0; gi < 4; ++gi) {
    int g = gi * 64 + u;
    const float* wi = Wih + g * 128;
    const float* wh = Whh + g * 64;
    float acc = bih[g] + bhh[g];
    for (int k = 0; k < 128; ++k) acc += qs[k] * wi[k];
    for (int k = 0; k < 64; ++k) acc += rl(hxv, k) * wh[k];
    g4[gi] = acc;
  }
  float ig = sigm(g4[0]), fg = sigm(g4[1]), gg = tanhf(g4[2]), og = sigm(g4[3]);
  float c = fg * cx[b * 64 + u] + ig * gg;
  cx[b * 64 + u] = c;
  hx[b * 64 + u] = og * tanhf(c);
}

// ---------------- Set2Set attention + readout (1 wave per graph, 40 nodes) ----------------
__global__ __launch_bounds__(64) void k_readout(const float* __restrict__ hh,
                                                const float* __restrict__ hx,
                                                float* __restrict__ qstar) {
  int b = blockIdx.x, lane = threadIdx.x;
  float qv = hx[b * 64 + lane];
  const float* hb = hh + (size_t)b * 40 * HDIM;
  float scm = -1e30f;
  if (lane < 40) {
    float acc = 0.f;
    for (int k = 0; k < 64; ++k) acc += hb[lane * 64 + k] * rl(qv, k);
    scm = acc;
  }
  float mx = scm;
  #pragma unroll
  for (int m = 1; m < 64; m <<= 1) mx = fmaxf(mx, __shfl_xor(mx, m, 64));
  float ex = (lane < 40) ? __expf(scm - mx) : 0.f;
  float den = ex;
  #pragma unroll
  for (int m = 1; m < 64; m <<= 1) den += __shfl_xor(den, m, 64);
  float alpha = ex / den;
  float ro = 0.f;
  for (int m = 0; m < 40; ++m) ro += rl(alpha, m) * hb[m * 64 + lane];
  qstar[b * 128 + lane] = qv;
  qstar[b * 128 + 64 + lane] = ro;
}

// ---------------- out = q_star @ W_out + b_out ----------------
__global__ __launch_bounds__(256) void k_out(const float* __restrict__ qstar,
                                             const float* __restrict__ Wout,  // [128][64]
                                             const float* __restrict__ bout,
                                             float* __restrict__ out) {
  int g = blockIdx.x * 256 + threadIdx.x;   // grid exact: B*64
  int b = g >> 6, c = g & 63;
  const float* qs = qstar + b * 128;
  float acc = bout[c];
  #pragma unroll 4
  for (int k = 0; k < 128; ++k) acc += qs[k] * Wout[k * 64 + c];
  out[g] = acc;
}

extern "C" void kernel_launch(void* const* d_in, const int* in_sizes, int n_in,
                              void* d_out, int out_size, void* d_ws, size_t ws_size,
                              hipStream_t stream) {
  const float* h    = (const float*)d_in[0];
  const float* e_f  = (const float*)d_in[1];
  const int*   src  = (const int*)  d_in[2];
  // d_in[3] = dst (structure: e/8), d_in[4] = graph_id (structure: n/40) — implicit
  const float* Wp   = (const float*)d_in[5];
  const float* Wpe  = (const float*)d_in[6];
  const float* Wn   = (const float*)d_in[7];
  const float* We   = (const float*)d_in[8];
  const float* atr  = (const float*)d_in[9];
  const float* Wsc  = (const float*)d_in[10];
  const float* cb   = (const float*)d_in[11];
  const float* Wih  = (const float*)d_in[12];
  const float* Whh  = (const float*)d_in[13];
  const float* bih  = (const float*)d_in[14];
  const float* bhh  = (const float*)d_in[15];
  const float* Wout = (const float*)d_in[16];
  const float* bout = (const float*)d_in[17];
  float* out = (float*)d_out;

  float* ws = (float*)d_ws;
  float* hh    = ws;                            // N*64 fp32
  float* du    = hh  + (size_t)NNODES * HDIM;   // N*4
  float* dv    = du  + (size_t)NNODES * 4;      // N*4
  float* qstar = dv  + (size_t)NNODES * 4;      // B*128
  float* hx    = qstar + (size_t)NGRAPH * 128;  // B*64
  float* cx    = hx    + (size_t)NGRAPH * 64;   // B*64
  float* Wc    = cx    + (size_t)NGRAPH * 64;   // 3*13*256
  ushort* hhb  = (ushort*)(Wc + 3 * EDIM * NHH);          // N*64 bf16
  ushort* wvb  = hhb + (size_t)NNODES * HDIM;             // N*256 bf16 (pos-major)
  ushort* aggb = wvb + (size_t)NNODES * NHH;              // N*256 bf16 (pos-major)
  ushort* WnT  = aggb + (size_t)NNODES * NHH;             // 3*256*64 bf16
  ushort* WsT  = WnT + (size_t)3 * NHH * HDIM;            // 3*64*256 bf16 (k-permuted)
  ushort* efb  = WsT + (size_t)3 * HDIM * NHH;            // (E+16)*16 bf16
  ushort* Wcb  = efb + (size_t)(NEDGES + 16) * 16;        // 3*256*32 bf16
  ushort* wqb  = Wcb + (size_t)3 * NHH * 32;              // 3*16*32 bf16

  // zero set2set state (q_star, hx, cx contiguous)
  hipMemsetAsync(qstar, 0, (size_t)NGRAPH * (128 + 64 + 64) * sizeof(float), stream);

  k_comb<<<3 * EDIM * NHH / 256, 256, 0, stream>>>(Wpe, We, Wc);
  k_wcb<<<3 * NHH * 32 / 256, 256, 0, stream>>>(Wc, Wcb);
  k_wqb<<<3 * 16 * 32 / 256, 256, 0, stream>>>(Wc, atr, wqb);
  k_ef<<<(NEDGES + 16) * 16 / 256, 256, 0, stream>>>(e_f, efb);
  k_tn<<<3 * NHH * HDIM / 256, 256, 0, stream>>>(Wn, WnT);
  k_ts<<<3 * HDIM * NHH / 256, 256, 0, stream>>>(Wsc, WsT);
  k_proj<<<NNODES * HDIM / 256, 256, 0, stream>>>(h, Wp, hh, hhb);

  for (int i = 0; i < 3; ++i) {
    const float* atr_i = atr + (size_t)i * 4 * 192;
    const ushort* WnT_i = WnT + (size_t)i * NHH * HDIM;
    const ushort* WsT_i = WsT + (size_t)i * HDIM * NHH;
    const ushort* Wcb_i = Wcb + (size_t)i * NHH * 32;
    const ushort* wqb_i = wqb + (size_t)i * 16 * 32;
    const float* cb_i  = cb  + (size_t)i * 64;
    k_wv<<<NNODES / 32, 256, 0, stream>>>(hhb, WnT_i, atr_i, wvb, du, dv);
    k_edge<<<2048, 256, 0, stream>>>(wvb, efb, src, Wcb_i, wqb_i, du, dv, aggb);
    k_scale<<<NNODES / 32, 256, 0, stream>>>(aggb, WsT_i, cb_i, hh, hhb);
  }

  for (int t = 0; t < 2; ++t) {
    k_lstm<<<NGRAPH, 64, 0, stream>>>(qstar, Wih, Whh, bih, bhh, hx, cx);
    k_readout<<<NGRAPH, 64, 0, stream>>>(hh, hx, qstar);
  }

  k_out<<<NGRAPH * 64 / 256, 256, 0, stream>>>(qstar, Wout, bout, out);
}